// Round 1
// baseline (225.863 us; speedup 1.0000x reference)
//
#include <hip/hip_runtime.h>
#include <hip/hip_bf16.h>

// Problem constants: B=256, T=256, C=384, H=64, MAX_REL=3 (causal -> idx 0..3 only)

typedef __attribute__((ext_vector_type(8))) __bf16 bf16x8;
typedef __attribute__((ext_vector_type(8))) short short8;
typedef __attribute__((ext_vector_type(4))) float f32x4;
typedef __attribute__((ext_vector_type(4))) int   i32x4;

#define MFMA16(A, B, C) __builtin_amdgcn_mfma_f32_16x16x32_bf16((A), (B), (C), 0, 0, 0)

__device__ __forceinline__ unsigned short f2bf(float f) {
    unsigned int u = __builtin_bit_cast(unsigned int, f);
    u = (u + 0x7FFFu + ((u >> 16) & 1u)) >> 16;   // RNE
    return (unsigned short)u;
}
__device__ __forceinline__ float bf2f(unsigned short s) {
    unsigned int u = ((unsigned int)s) << 16;
    return __builtin_bit_cast(float, u);
}
__device__ __forceinline__ bf16x8 ld16(const unsigned short* p) {
    return __builtin_bit_cast(bf16x8, *(const i32x4*)p);
}

// ---------------------------------------------------------------------------
// Kernel 0: Wt[3][64][384] bf16  =  transpose+convert of Wq/Wk/Wv [384][64] f32
// ---------------------------------------------------------------------------
__global__ void prep_wt(const float* __restrict__ Wq, const float* __restrict__ Wk,
                        const float* __restrict__ Wv, unsigned short* __restrict__ Wt) {
    int i = blockIdx.x * 256 + threadIdx.x;           // 3*64*384 = 73728
    if (i >= 3 * 64 * 384) return;
    int kk = i % 384;
    int h  = (i / 384) & 63;
    int w  = i / (384 * 64);
    const float* W = (w == 0) ? Wq : ((w == 1) ? Wk : Wv);
    Wt[i] = f2bf(W[kk * 64 + h]);
}

// ---------------------------------------------------------------------------
// Kernel 1: fused QKV projection.
//   q[M][64] bf16, k[M][64] bf16, vT[b][64][256] bf16  (M = B*T = 65536)
//   Block: 512 thr (8 waves), 128 rows. x read once (fp32 -> bf16 in reg).
//   Wt staged via LDS in 3 chunks of 128 k (rows padded to 136 -> b128 reads
//   land 2 lanes/bank = free).
//   vT uses swapped MFMA operands: A = Wv^T rows (m=h), B = x rows (n=t);
//   the x B-fragment equals the x A-fragment bit-for-bit (same lane->row map).
// ---------------------------------------------------------------------------
__global__ __launch_bounds__(512) void qkv_kernel(
        const float* __restrict__ x, const unsigned short* __restrict__ Wt,
        unsigned short* __restrict__ q, unsigned short* __restrict__ k,
        unsigned short* __restrict__ vT) {
    __shared__ unsigned short wlds[192][136];          // 52224 B

    const int tid  = threadIdx.x;
    const int wave = tid >> 6;
    const int lane = tid & 63;
    const int c    = lane & 15;
    const int quad = lane >> 4;
    const int M0   = blockIdx.x * 128;
    const int myrow = M0 + wave * 16 + c;              // x row owned by this lane

    f32x4 zero = {0.f, 0.f, 0.f, 0.f};
    f32x4 aq[4], ak[4], av[4];
#pragma unroll
    for (int i = 0; i < 4; i++) { aq[i] = zero; ak[i] = zero; av[i] = zero; }

    for (int ck = 0; ck < 3; ck++) {
        if (ck) __syncthreads();                       // prev chunk reads done
        // stage Wt chunk: rows 0..191, k in [128*ck, 128*ck+128)
#pragma unroll
        for (int it = 0; it < 6; it++) {
            int i = it * 512 + tid;                    // 192*16 = 3072 16B pieces
            int r = i >> 4, kc = i & 15;
            i32x4 d = *(const i32x4*)(Wt + r * 384 + ck * 128 + kc * 8);
            *(i32x4*)(&wlds[r][kc * 8]) = d;
        }
        __syncthreads();

#pragma unroll
        for (int ks = 0; ks < 4; ks++) {
            // x fragment (A for q/k, B for vT): 8 fp32 -> bf16
            const float* xp = x + (size_t)myrow * 384 + ck * 128 + ks * 32 + quad * 8;
            f32x4 x0 = *(const f32x4*)xp;
            f32x4 x1 = *(const f32x4*)(xp + 4);
            short8 xs;
#pragma unroll
            for (int j = 0; j < 4; j++) {
                xs[j]     = (short)f2bf(x0[j]);
                xs[4 + j] = (short)f2bf(x1[j]);
            }
            bf16x8 a = __builtin_bit_cast(bf16x8, xs);

#pragma unroll
            for (int nt = 0; nt < 8; nt++) {           // q: nt 0..3, k: nt 4..7
                bf16x8 b = ld16(&wlds[nt * 16 + c][ks * 32 + quad * 8]);
                if (nt < 4) aq[nt]     = MFMA16(a, b, aq[nt]);
                else        ak[nt - 4] = MFMA16(a, b, ak[nt - 4]);
            }
#pragma unroll
            for (int mt = 0; mt < 4; mt++) {           // vT: A = Wv^T rows
                bf16x8 aw = ld16(&wlds[128 + mt * 16 + c][ks * 32 + quad * 8]);
                av[mt] = MFMA16(aw, a, av[mt]);
            }
        }
    }

    // epilogue: C/D layout col=lane&15, row=quad*4+reg
    const int b   = M0 >> 8;
    const int t0b = M0 & 255;
#pragma unroll
    for (int nt = 0; nt < 4; nt++) {
#pragma unroll
        for (int r = 0; r < 4; r++) {
            int row = M0 + wave * 16 + quad * 4 + r;
            q[row * 64 + nt * 16 + c] = f2bf(aq[nt][r]);
            k[row * 64 + nt * 16 + c] = f2bf(ak[nt][r]);
        }
    }
#pragma unroll
    for (int mt = 0; mt < 4; mt++) {
#pragma unroll
        for (int r = 0; r < 4; r++) {
            int h = mt * 16 + quad * 4 + r;
            vT[(b * 64 + h) * 256 + t0b + wave * 16 + c] = f2bf(av[mt][r]);
        }
    }
}

// ---------------------------------------------------------------------------
// Kernel 2: causal attention with Shaw relative positions.
//   Grid (4, 256): blockIdx.x = q-tile tt (64 rows), blockIdx.y = batch.
//   Block 256 thr (4 waves); wave w owns rows t0+16w .. +15.
//   Scores in accumulators; E[r][j]=q_row . rel_k[j] (j=0..3) precomputed;
//   softmax via quad shuffles; P -> LDS bf16 (stride 264) -> A-frags for P@V;
//   w2 from the 3 band probabilities (row-sum-to-1 identity).
// ---------------------------------------------------------------------------
__global__ __launch_bounds__(256) void attn_kernel(
        const unsigned short* __restrict__ q, const unsigned short* __restrict__ k,
        const unsigned short* __restrict__ vT,
        const float* __restrict__ relk, const float* __restrict__ relv,
        float* __restrict__ out) {
    __shared__ unsigned short P[64][264];              // 33792 B, stride 528 B
    __shared__ float E[64][4];

    const int tid  = threadIdx.x;
    const int wave = tid >> 6;
    const int lane = tid & 63;
    const int c    = lane & 15;
    const int quad = lane >> 4;
    const int tt   = blockIdx.x;
    const int b    = blockIdx.y;
    const int t0   = tt * 64;
    const int nst  = 4 * (tt + 1);                     // valid 16-wide s-tiles

    // Phase 0: E[r][j] = q[b][t0+r] . rel_k[j], j = 0..3
    {
        int r = tid >> 2, j = tid & 3;
        const unsigned short* qr = q + (size_t)(b * 256 + t0 + r) * 64;
        const float* rk = relk + j * 64;
        float e = 0.f;
#pragma unroll
        for (int hh = 0; hh < 64; hh += 8) {
            i32x4 d = *(const i32x4*)(qr + hh);
            const unsigned short* u = (const unsigned short*)&d;
#pragma unroll
            for (int j2 = 0; j2 < 8; j2++) e += bf2f(u[j2]) * rk[hh + j2];
        }
        E[r][j] = e;
    }
    __syncthreads();

    // q A-frags for this lane's row (m = lane&15)
    const unsigned short* qp = q + (size_t)(b * 256 + t0 + wave * 16 + c) * 64 + quad * 8;
    bf16x8 aq0 = ld16(qp);
    bf16x8 aq1 = ld16(qp + 32);

    // Phase 1: S = Q K^T over valid s-tiles
    f32x4 s[16];
    f32x4 zero = {0.f, 0.f, 0.f, 0.f};
#pragma unroll
    for (int st = 0; st < 16; st++) s[st] = zero;
#pragma unroll
    for (int st = 0; st < 16; st++) {
        if (st < nst) {
            const unsigned short* kp = k + (size_t)(b * 256 + st * 16 + c) * 64 + quad * 8;
            s[st] = MFMA16(aq0, ld16(kp), s[st]);
            s[st] = MFMA16(aq1, ld16(kp + 32), s[st]);
        }
    }

    // Phase 2: rel-pos add + scale + causal mask; row max
    const int rbase = wave * 16 + quad * 4;            // local row (0..63) base
    f32x4 ef[4];
#pragma unroll
    for (int r = 0; r < 4; r++) ef[r] = *(const f32x4*)(&E[rbase + r][0]);

    float m[4] = {-3.0e38f, -3.0e38f, -3.0e38f, -3.0e38f};
#pragma unroll
    for (int st = 0; st < 16; st++) {
        if (st < nst) {
#pragma unroll
            for (int r = 0; r < 4; r++) {
                int tl = rbase + r;                    // local row
                int d  = st * 16 + c - (t0 + tl);      // s - t
                float e  = (d <= -3) ? ef[r][0] : (d == -2) ? ef[r][1]
                         : (d == -1) ? ef[r][2] : ef[r][3];
                float sc = (d > 0) ? -1.0e30f : 0.125f * (s[st][r] + e);
                s[st][r] = sc;
                m[r] = fmaxf(m[r], sc);
            }
        }
    }
#pragma unroll
    for (int r = 0; r < 4; r++)
#pragma unroll
        for (int ofs = 1; ofs < 16; ofs <<= 1)
            m[r] = fmaxf(m[r], __shfl_xor(m[r], ofs, 64));

    // Phase 3: exp + row sum + normalize; write P (bf16) to LDS
    float l[4] = {0.f, 0.f, 0.f, 0.f};
#pragma unroll
    for (int st = 0; st < 16; st++) {
        if (st < nst) {
#pragma unroll
            for (int r = 0; r < 4; r++) {
                float p = __expf(s[st][r] - m[r]);
                s[st][r] = p;
                l[r] += p;
            }
        }
    }
#pragma unroll
    for (int r = 0; r < 4; r++)
#pragma unroll
        for (int ofs = 1; ofs < 16; ofs <<= 1)
            l[r] += __shfl_xor(l[r], ofs, 64);
    float rl[4];
#pragma unroll
    for (int r = 0; r < 4; r++) rl[r] = 1.0f / l[r];

#pragma unroll
    for (int st = 0; st < 16; st++) {
        if (st < nst) {
#pragma unroll
            for (int r = 0; r < 4; r++)
                P[rbase + r][st * 16 + c] = f2bf(s[st][r] * rl[r]);
        }
    }
    __syncthreads();

    // Phase 4: O = P @ V  (A = P rows from LDS, B = vT rows from global)
    f32x4 o[4];
#pragma unroll
    for (int nt = 0; nt < 4; nt++) o[nt] = zero;
    const int ksteps = nst >> 1;
#pragma unroll
    for (int ks = 0; ks < 8; ks++) {
        if (ks < ksteps) {
            bf16x8 ap = ld16(&P[wave * 16 + c][ks * 32 + quad * 8]);
#pragma unroll
            for (int nt = 0; nt < 4; nt++) {
                const unsigned short* vp = vT + (size_t)(b * 64 + nt * 16 + c) * 256
                                              + ks * 32 + quad * 8;
                o[nt] = MFMA16(ap, ld16(vp), o[nt]);
            }
        }
    }

    // Phase 5: w2 from band probabilities + store
#pragma unroll
    for (int r = 0; r < 4; r++) {
        int tl = rbase + r;
        int tg = t0 + tl;
        int ia = (tg >= 2) ? tg - 2 : 0;
        int ib = (tg >= 1) ? tg - 1 : 0;
        float pa = (tg >= 2) ? bf2f(P[tl][ia]) : 0.f;
        float pb = (tg >= 1) ? bf2f(P[tl][ib]) : 0.f;
        float pc = bf2f(P[tl][tg]);
#pragma unroll
        for (int nt = 0; nt < 4; nt++) {
            int h = nt * 16 + c;
            float r0 = relv[h], r1 = relv[64 + h], r2 = relv[128 + h], r3 = relv[192 + h];
            float w2 = r0 + pa * (r1 - r0) + pb * (r2 - r0) + pc * (r3 - r0);
            out[(size_t)(b * 256 + tg) * 64 + h] = o[nt][r] + w2;
        }
    }
}

// ---------------------------------------------------------------------------
extern "C" void kernel_launch(void* const* d_in, const int* in_sizes, int n_in,
                              void* d_out, int out_size, void* d_ws, size_t ws_size,
                              hipStream_t stream) {
    const float* x    = (const float*)d_in[0];
    const float* Wq   = (const float*)d_in[1];
    const float* Wk   = (const float*)d_in[2];
    const float* Wv   = (const float*)d_in[3];
    const float* relk = (const float*)d_in[4];
    const float* relv = (const float*)d_in[5];
    float* out = (float*)d_out;

    char* ws = (char*)d_ws;
    unsigned short* q  = (unsigned short*)(ws);                 // 65536*64 bf16 = 8 MiB
    unsigned short* kk = (unsigned short*)(ws + 8388608);       // 8 MiB
    unsigned short* vT = (unsigned short*)(ws + 16777216);      // 8 MiB
    unsigned short* Wt = (unsigned short*)(ws + 25165824);      // 144 KiB

    prep_wt<<<288, 256, 0, stream>>>(Wq, Wk, Wv, Wt);
    qkv_kernel<<<512, 512, 0, stream>>>(x, Wt, q, kk, vT);
    attn_kernel<<<dim3(4, 256), 256, 0, stream>>>(q, kk, vT, relk, relv, out);
}

// Round 2
// 212.929 us; speedup vs baseline: 1.0607x; 1.0607x over previous
//
#include <hip/hip_runtime.h>
#include <hip/hip_bf16.h>

// Problem: B=256, T=256, C=384, H=64, MAX_REL=3 (causal -> rel idx 0..3 only)
// Fused design: prep_wt (weight transpose->bf16) + ONE kernel, block = batch.

typedef __attribute__((ext_vector_type(8))) __bf16 bf16x8;
typedef __attribute__((ext_vector_type(8))) short short8;
typedef __attribute__((ext_vector_type(4))) float f32x4;
typedef __attribute__((ext_vector_type(4))) int   i32x4;

#define MFMA16(A, B, C) __builtin_amdgcn_mfma_f32_16x16x32_bf16((A), (B), (C), 0, 0, 0)

__device__ __forceinline__ unsigned short f2bf(float f) {
    unsigned int u = __builtin_bit_cast(unsigned int, f);
    u = (u + 0x7FFFu + ((u >> 16) & 1u)) >> 16;   // RNE
    return (unsigned short)u;
}
__device__ __forceinline__ float bf2f(unsigned short s) {
    unsigned int u = ((unsigned int)s) << 16;
    return __builtin_bit_cast(float, u);
}
__device__ __forceinline__ bf16x8 ld16(const unsigned short* p) {
    return __builtin_bit_cast(bf16x8, *(const i32x4*)p);
}

// ---------------------------------------------------------------------------
// Kernel 0: Wt[3][64][384] bf16 = transpose+convert of Wq/Wk/Wv [384][64] f32
// ---------------------------------------------------------------------------
__global__ void prep_wt(const float* __restrict__ Wq, const float* __restrict__ Wk,
                        const float* __restrict__ Wv, unsigned short* __restrict__ Wt) {
    int i = blockIdx.x * 256 + threadIdx.x;           // 3*64*384 = 73728
    if (i >= 3 * 64 * 384) return;
    int kk = i % 384;
    int h  = (i / 384) & 63;
    int w  = i / (384 * 64);
    const float* W = (w == 0) ? Wq : ((w == 1) ? Wk : Wv);
    Wt[i] = f2bf(W[kk * 64 + h]);
}

// ---------------------------------------------------------------------------
// Fused kernel: one block (256 thr, 4 waves) per batch.
//   Phase A: QKV projection. x read from global once (f32 -> bf16 in reg);
//            Wt fragments read directly from global (L2-resident, 147 KB).
//            Wave w owns t-rows [64w, 64w+64). q,k -> LDS [t][h]; v -> LDS
//            transposed [h][t] via swapped MFMA operands (A = Wv^T rows).
//   Phase B: E[t][j] = q_t . rel_k[j], j=0..3 (only idx 0..3 survive causal).
//   Phase C: per 64-row q-tile: S=QK^T (MFMA, LDS frags), rel+mask epilogue,
//            quad-shuffle softmax, P (wave-private LDS rows) -> A-frags,
//            O = P@V (vT frags from LDS), w2 via band-probability identity
//            (softmax rows sum to 1 -> only P[t,t], P[t,t-1], P[t,t-2] needed).
// LDS map (dynamic, 145408 B total):
//   qs  [256][72] u16 @ 0        36864   (stride 144B = 36 dw == 4 mod 8: balanced b128 banks)
//   kk  [256][72] u16 @ 36864    36864
//   vs  [64][264] u16 @ 73728    33792
//   P   [64][264] u16 @ 107520   33792   (wave-private rows 16w..16w+15)
//   E   [256][4]  f32 @ 141312    4096
// ---------------------------------------------------------------------------
__global__ __launch_bounds__(256, 1) void fused_kernel(
        const float* __restrict__ x, const unsigned short* __restrict__ Wt,
        const float* __restrict__ relk, const float* __restrict__ relv,
        float* __restrict__ out) {
    extern __shared__ char smem[];
    unsigned short* qs = (unsigned short*)(smem);           // [256][72]
    unsigned short* kl = (unsigned short*)(smem + 36864);   // [256][72]
    unsigned short* vs = (unsigned short*)(smem + 73728);   // [64][264]
    unsigned short* P  = (unsigned short*)(smem + 107520);  // [64][264]
    float*          E  = (float*)(smem + 141312);           // [256][4]

    const int tid  = threadIdx.x;
    const int wave = tid >> 6;
    const int lane = tid & 63;
    const int c    = lane & 15;
    const int quad = lane >> 4;
    const int b    = blockIdx.x;

    f32x4 zero = {0.f, 0.f, 0.f, 0.f};

    // ---------------- Phase A: QKV projection ----------------
    f32x4 accq[4][4], acck[4][4], accv[4][4];
#pragma unroll
    for (int i = 0; i < 4; i++)
#pragma unroll
        for (int j = 0; j < 4; j++) { accq[i][j] = zero; acck[i][j] = zero; accv[i][j] = zero; }

    const float* xb = x + (size_t)b * 256 * 384;
#pragma unroll
    for (int kc = 0; kc < 12; kc++) {
        const int ko = kc * 32 + quad * 8;
        // x A-frags for this wave's 4 m-tiles (rows 64w + 16mt + c)
        bf16x8 a[4];
#pragma unroll
        for (int mt = 0; mt < 4; mt++) {
            const float* xp = xb + (wave * 64 + mt * 16 + c) * 384 + ko;
            f32x4 x0 = *(const f32x4*)xp;
            f32x4 x1 = *(const f32x4*)(xp + 4);
            short8 xs;
#pragma unroll
            for (int j = 0; j < 4; j++) { xs[j] = (short)f2bf(x0[j]); xs[4 + j] = (short)f2bf(x1[j]); }
            a[mt] = __builtin_bit_cast(bf16x8, xs);
        }
        // weight fragments straight from global (L2-hot)
        bf16x8 bq[4], bk[4], aw[4];
#pragma unroll
        for (int nt = 0; nt < 4; nt++) {
            bq[nt] = ld16(Wt + (nt * 16 + c) * 384 + ko);          // Wq^T rows
            bk[nt] = ld16(Wt + (64 + nt * 16 + c) * 384 + ko);     // Wk^T rows
            aw[nt] = ld16(Wt + (128 + nt * 16 + c) * 384 + ko);    // Wv^T rows (A-op for vT)
        }
#pragma unroll
        for (int mt = 0; mt < 4; mt++)
#pragma unroll
            for (int nt = 0; nt < 4; nt++) {
                accq[mt][nt] = MFMA16(a[mt], bq[nt], accq[mt][nt]);   // D[t][h]
                acck[mt][nt] = MFMA16(a[mt], bk[nt], acck[mt][nt]);   // D[t][h]
                accv[nt][mt] = MFMA16(aw[nt], a[mt], accv[nt][mt]);   // D[h][t]
            }
    }
    // epilogue: C/D layout col=lane&15, row=quad*4+reg
#pragma unroll
    for (int mt = 0; mt < 4; mt++)
#pragma unroll
        for (int nt = 0; nt < 4; nt++)
#pragma unroll
            for (int r = 0; r < 4; r++) {
                int row = wave * 64 + mt * 16 + quad * 4 + r;
                qs[row * 72 + nt * 16 + c] = f2bf(accq[mt][nt][r]);
                kl[row * 72 + nt * 16 + c] = f2bf(acck[mt][nt][r]);
                vs[(nt * 16 + quad * 4 + r) * 264 + wave * 64 + mt * 16 + c] = f2bf(accv[nt][mt][r]);
            }
    __syncthreads();

    // ---------------- Phase B: E[t][j] = q_t . rel_k[j] ----------------
#pragma unroll
    for (int it = 0; it < 4; it++) {
        int rr = it * 64 + (tid >> 2);
        int j  = tid & 3;
        const unsigned short* qr = qs + rr * 72;
        const float* rk = relk + j * 64;
        float e = 0.f;
#pragma unroll
        for (int hh = 0; hh < 64; hh += 8) {
            i32x4 d = *(const i32x4*)(qr + hh);
            const unsigned short* u = (const unsigned short*)&d;
#pragma unroll
            for (int j2 = 0; j2 < 8; j2++) e += bf2f(u[j2]) * rk[hh + j2];
        }
        E[rr * 4 + j] = e;
    }
    __syncthreads();

    // ---------------- Phase C: attention over 4 q-tiles ----------------
    for (int tt = 0; tt < 4; tt++) {
        const int t0  = tt * 64;
        const int nst = 4 * (tt + 1);                  // valid 16-wide s-tiles

        const unsigned short* qp = qs + (t0 + wave * 16 + c) * 72 + quad * 8;
        bf16x8 aq0 = ld16(qp);
        bf16x8 aq1 = ld16(qp + 32);

        // S = Q K^T
        f32x4 s[16];
#pragma unroll
        for (int st = 0; st < 16; st++) s[st] = zero;
#pragma unroll
        for (int st = 0; st < 16; st++) {
            if (st < nst) {
                const unsigned short* kp = kl + (st * 16 + c) * 72 + quad * 8;
                s[st] = MFMA16(aq0, ld16(kp), s[st]);
                s[st] = MFMA16(aq1, ld16(kp + 32), s[st]);
            }
        }

        // rel-pos add + scale + causal mask; row max
        const int rbase = wave * 16 + quad * 4;        // local row base (0..63)
        f32x4 ef[4];
#pragma unroll
        for (int r = 0; r < 4; r++) ef[r] = *(const f32x4*)(E + (t0 + rbase + r) * 4);

        float m[4] = {-3.0e38f, -3.0e38f, -3.0e38f, -3.0e38f};
#pragma unroll
        for (int st = 0; st < 16; st++) {
            if (st < nst) {
#pragma unroll
                for (int r = 0; r < 4; r++) {
                    int tl = rbase + r;
                    int d  = st * 16 + c - (t0 + tl);  // s - t
                    float e  = (d <= -3) ? ef[r][0] : (d == -2) ? ef[r][1]
                             : (d == -1) ? ef[r][2] : ef[r][3];
                    float sc = (d > 0) ? -1.0e30f : 0.125f * (s[st][r] + e);
                    s[st][r] = sc;
                    m[r] = fmaxf(m[r], sc);
                }
            }
        }
#pragma unroll
        for (int r = 0; r < 4; r++)
#pragma unroll
            for (int ofs = 1; ofs < 16; ofs <<= 1)
                m[r] = fmaxf(m[r], __shfl_xor(m[r], ofs, 64));

        // exp + row sum + normalize; write P (bf16, wave-private rows)
        float l[4] = {0.f, 0.f, 0.f, 0.f};
#pragma unroll
        for (int st = 0; st < 16; st++) {
            if (st < nst) {
#pragma unroll
                for (int r = 0; r < 4; r++) {
                    float p = __expf(s[st][r] - m[r]);
                    s[st][r] = p;
                    l[r] += p;
                }
            }
        }
#pragma unroll
        for (int r = 0; r < 4; r++)
#pragma unroll
            for (int ofs = 1; ofs < 16; ofs <<= 1)
                l[r] += __shfl_xor(l[r], ofs, 64);
        float rl[4];
#pragma unroll
        for (int r = 0; r < 4; r++) rl[r] = 1.0f / l[r];

#pragma unroll
        for (int st = 0; st < 16; st++) {
            if (st < nst) {
#pragma unroll
                for (int r = 0; r < 4; r++)
                    P[(rbase + r) * 264 + st * 16 + c] = f2bf(s[st][r] * rl[r]);
            }
        }
        __syncthreads();

        // O = P @ V  (A = P rows, B = vT rows, both LDS)
        f32x4 o[4];
#pragma unroll
        for (int nt = 0; nt < 4; nt++) o[nt] = zero;
        const int ksteps = nst >> 1;
#pragma unroll
        for (int ks = 0; ks < 8; ks++) {
            if (ks < ksteps) {
                bf16x8 ap = ld16(P + (wave * 16 + c) * 264 + ks * 32 + quad * 8);
#pragma unroll
                for (int nt = 0; nt < 4; nt++) {
                    const unsigned short* vp = vs + (nt * 16 + c) * 264 + ks * 32 + quad * 8;
                    o[nt] = MFMA16(ap, ld16(vp), o[nt]);
                }
            }
        }

        // w2 from band probabilities + store
#pragma unroll
        for (int r = 0; r < 4; r++) {
            int tl = rbase + r;
            int tg = t0 + tl;
            int ia = (tg >= 2) ? tg - 2 : 0;
            int ib = (tg >= 1) ? tg - 1 : 0;
            float pa = (tg >= 2) ? bf2f(P[tl * 264 + ia]) : 0.f;
            float pb = (tg >= 1) ? bf2f(P[tl * 264 + ib]) : 0.f;
            float pc = bf2f(P[tl * 264 + tg]);
#pragma unroll
            for (int nt = 0; nt < 4; nt++) {
                int h = nt * 16 + c;
                float r0 = relv[h], r1 = relv[64 + h], r2 = relv[128 + h], r3 = relv[192 + h];
                float w2 = r0 + pa * (r1 - r0) + pb * (r2 - r0) + pc * (r3 - r0);
                out[(size_t)(b * 256 + tg) * 64 + h] = o[nt][r] + w2;
            }
        }
        __syncthreads();
    }
}

// ---------------------------------------------------------------------------
extern "C" void kernel_launch(void* const* d_in, const int* in_sizes, int n_in,
                              void* d_out, int out_size, void* d_ws, size_t ws_size,
                              hipStream_t stream) {
    const float* x    = (const float*)d_in[0];
    const float* Wq   = (const float*)d_in[1];
    const float* Wk   = (const float*)d_in[2];
    const float* Wv   = (const float*)d_in[3];
    const float* relk = (const float*)d_in[4];
    const float* relv = (const float*)d_in[5];
    float* out = (float*)d_out;

    unsigned short* Wt = (unsigned short*)d_ws;        // 3*64*384 bf16 = 144 KiB

    // opt-in to >64KB dynamic LDS (idempotent; non-stream op, capture-safe)
    (void)hipFuncSetAttribute((const void*)fused_kernel,
                              hipFuncAttributeMaxDynamicSharedMemorySize, 145408);

    prep_wt<<<288, 256, 0, stream>>>(Wq, Wk, Wv, Wt);
    fused_kernel<<<256, 256, 145408, stream>>>(x, Wt, relk, relv, out);
}